// Round 4
// baseline (2851.006 us; speedup 1.0000x reference)
//
#include <hip/hip_runtime.h>
#include <hip/hip_bf16.h>

#define NN 20000
#define TT 16
#define EE 320000
#define CC 128
#define HH 128
#define PP 100000

typedef __bf16 bf16x8 __attribute__((ext_vector_type(8)));
typedef float  f32x4  __attribute__((ext_vector_type(4)));
typedef unsigned short ushort4v __attribute__((ext_vector_type(4)));
typedef unsigned short ushort8v __attribute__((ext_vector_type(8)));
typedef _Float16 h2v __attribute__((ext_vector_type(2)));
typedef _Float16 h4v __attribute__((ext_vector_type(4)));

typedef union { ushort8v u; bf16x8 b; } cvt8;

__device__ __forceinline__ unsigned short f2bf(float x) {
    union { float f; unsigned u; } v; v.f = x;
    unsigned r = v.u + 0x7FFF + ((v.u >> 16) & 1);
    return (unsigned short)(r >> 16);
}
__device__ __forceinline__ float bf2f(unsigned short h) {
    union { unsigned u; float f; } v; v.u = ((unsigned)h) << 16; return v.f;
}

// ---------------- batched CSR build ----------------

__global__ void hist_all_k(const int* __restrict__ edge_index, int* __restrict__ cnt_all) {
    int e = blockIdx.x * blockDim.x + threadIdx.x;
    int f = blockIdx.y;
    if (e < EE) {
        const int* dst = edge_index + (size_t)f * 2 * EE + EE;
        atomicAdd(&cnt_all[f * NN + dst[e]], 1);
    }
}

// one block per frame; also emits dinv and cursor (= csr fill position, frame-based)
__global__ __launch_bounds__(1024) void scan_all_k(const int* __restrict__ cnt_all,
                                                   int* __restrict__ offs_all,
                                                   float* __restrict__ dinv_all,
                                                   int* __restrict__ cursor_all) {
    __shared__ int part[1024];
    int f = blockIdx.x;
    const int* cnt = cnt_all + f * NN;
    int* offs = offs_all + f * (NN + 1);
    int t = threadIdx.x;
    int base = t * 20;
    int vals[20];
    int s = 0;
#pragma unroll
    for (int i = 0; i < 20; ++i) {
        int idx = base + i;
        int v = (idx < NN) ? cnt[idx] : 0;
        vals[i] = v; s += v;
    }
    part[t] = s;
    __syncthreads();
    for (int off = 1; off < 1024; off <<= 1) {
        int v = (t >= off) ? part[t - off] : 0;
        __syncthreads();
        part[t] += v;
        __syncthreads();
    }
    int run = part[t] - s;
#pragma unroll
    for (int i = 0; i < 20; ++i) {
        int idx = base + i;
        if (idx < NN) {
            offs[idx] = run;
            cursor_all[f * NN + idx] = f * EE + run;   // absolute csr fill pos
            dinv_all[f * NN + idx] = rsqrtf((float)vals[i] + 1.0f);
            run += vals[i];
        }
    }
    if (t == 0) offs[NN] = EE;
}

__global__ void fill_all_k(const int* __restrict__ edge_index,
                           int* __restrict__ cursor_all, int* __restrict__ csr_all) {
    int e = blockIdx.x * blockDim.x + threadIdx.x;
    int f = blockIdx.y;
    if (e < EE) {
        const int* src = edge_index + (size_t)f * 2 * EE;
        const int* dst = src + EE;
        int d = dst[e];
        int pos = atomicAdd(&cursor_all[f * NN + d], 1);
        csr_all[pos] = src[e];
    }
}

// ---------------- weight prep ----------------
__global__ void wprep_t_k(const float* __restrict__ W,
                          unsigned short* __restrict__ oh,
                          unsigned short* __restrict__ ol) {
    int i = blockIdx.x * blockDim.x + threadIdx.x;
    if (i >= 128 * 128) return;
    int n = i >> 7, k = i & 127;
    float v = W[k * 128 + n];
    unsigned short h = f2bf(v);
    oh[i] = h;
    ol[i] = f2bf(v - bf2f(h));
}

__global__ void wprep_d_k(const float* __restrict__ w,
                          unsigned short* __restrict__ oh,
                          unsigned short* __restrict__ ol, int n) {
    int i = blockIdx.x * blockDim.x + threadIdx.x;
    if (i >= n) return;
    float v = w[i];
    unsigned short h = f2bf(v);
    oh[i] = h;
    ol[i] = f2bf(v - bf2f(h));
}

// ---------------- g0 = dinv ⊙ x  (fp32 -> fp16) ----------------
__global__ __launch_bounds__(256) void scale_k(const float* __restrict__ x,
                                               const float* __restrict__ dinv_all,
                                               _Float16* __restrict__ g) {
    int idx = blockIdx.x * blockDim.x + threadIdx.x;   // 320000*32
    int row = idx >> 5, q = idx & 31;
    float4 v = *(const float4*)(x + (size_t)row * 128 + q * 4);
    float d = dinv_all[row];
    h4v o;
    o.x = (_Float16)(v.x * d); o.y = (_Float16)(v.y * d);
    o.z = (_Float16)(v.z * d); o.w = (_Float16)(v.w * d);
    *(h4v*)(g + (size_t)row * 128 + q * 4) = o;
}

// ---------------- aggregation: a[n] = sum_{s in N(n)} g[s] + g[n]  (fp16 io, fp32 acc) ----------------
__global__ __launch_bounds__(128) void agg_f16_k(const _Float16* __restrict__ g,
                                                 const int* __restrict__ csr_all,
                                                 const int* __restrict__ offs_all,
                                                 _Float16* __restrict__ a) {
    int n = blockIdx.x * 2 + (threadIdx.x >> 6);
    int f = blockIdx.y;
    int lane = threadIdx.x & 63;
    const int* offs = offs_all + f * (NN + 1);
    const int* csr = csr_all + (size_t)f * EE;
    const _Float16* gf = g + (size_t)f * NN * HH;
    int beg = offs[n], end = offs[n + 1];
    float a0 = 0.f, a1 = 0.f;
    int e = beg;
    for (; e + 3 < end; e += 4) {
        int s0 = csr[e], s1 = csr[e + 1], s2 = csr[e + 2], s3 = csr[e + 3];
        h2v v0 = *(const h2v*)(gf + (size_t)s0 * HH + lane * 2);
        h2v v1 = *(const h2v*)(gf + (size_t)s1 * HH + lane * 2);
        h2v v2 = *(const h2v*)(gf + (size_t)s2 * HH + lane * 2);
        h2v v3 = *(const h2v*)(gf + (size_t)s3 * HH + lane * 2);
        a0 += ((float)v0.x + (float)v1.x) + ((float)v2.x + (float)v3.x);
        a1 += ((float)v0.y + (float)v1.y) + ((float)v2.y + (float)v3.y);
    }
    for (; e < end; ++e) {
        h2v v = *(const h2v*)(gf + (size_t)csr[e] * HH + lane * 2);
        a0 += (float)v.x; a1 += (float)v.y;
    }
    h2v vs = *(const h2v*)(gf + (size_t)n * HH + lane * 2);
    a0 += (float)vs.x; a1 += (float)vs.y;
    h2v r; r.x = (_Float16)a0; r.y = (_Float16)a1;
    *(h2v*)(a + ((size_t)f * NN + n) * HH + lane * 2) = r;
}

// ---------------- split-bf16 MFMA GEMM, fp16 A input, fp16 output ----------------
// out = epilogue(A[M][128] @ B^T), B bf16 hi/lo [NC][128].
// epilogue: v = acc; if(rowscale) v*=rs[r]; v+=bias[c]; if(relu) v=max(v,0); if(postscale) v*=rs[r];
__global__ __launch_bounds__(256) void gemm_f16(const _Float16* __restrict__ A,
                                                const unsigned short* __restrict__ Bh,
                                                const unsigned short* __restrict__ Bl,
                                                _Float16* __restrict__ out,
                                                const float* __restrict__ rowscale,
                                                const float* __restrict__ bias,
                                                int M, int NC, int relu, int postscale) {
    __shared__ unsigned short Ahs[64 * 72], Als[64 * 72], Bhs[64 * 72], Bls[64 * 72];
    int t = threadIdx.x;
    int row0 = blockIdx.x * 64, col0 = blockIdx.y * 64;
    int w = t >> 6, lane = t & 63;
    int wm = (w & 1) * 32, wn = (w >> 1) * 32;
    int lm = lane & 15, lq = lane >> 4;
    f32x4 acc[2][2] = {};

    for (int ks = 0; ks < 2; ++ks) {
        if (ks) __syncthreads();
        // stage A: 64 rows x 64 k (fp16 -> exact hi/lo bf16 split)
#pragma unroll
        for (int p = 0; p < 2; ++p) {
            int s = t + p * 256;           // 512 slots
            int r = s >> 3, c8 = s & 7;
            int gr = row0 + r;
            h2v v4[4] = {};
            if (gr < M) {
#pragma unroll
                for (int q = 0; q < 4; ++q)
                    v4[q] = *(const h2v*)(A + (size_t)gr * 128 + ks * 64 + c8 * 8 + q * 2);
            }
            cvt8 hh, ll;
#pragma unroll
            for (int q = 0; q < 4; ++q) {
                float f0 = (float)v4[q].x, f1 = (float)v4[q].y;
                unsigned short h0 = f2bf(f0), h1 = f2bf(f1);
                hh.u[q * 2] = h0;     ll.u[q * 2] = f2bf(f0 - bf2f(h0));
                hh.u[q * 2 + 1] = h1; ll.u[q * 2 + 1] = f2bf(f1 - bf2f(h1));
            }
            *(ushort8v*)&Ahs[r * 72 + c8 * 8] = hh.u;
            *(ushort8v*)&Als[r * 72 + c8 * 8] = ll.u;
        }
        // stage B
#pragma unroll
        for (int p = 0; p < 2; ++p) {
            int s = t + p * 256;
            int n = s >> 3, c = s & 7;
            *(ushort8v*)&Bhs[n * 72 + c * 8] =
                *(const ushort8v*)(Bh + (size_t)(col0 + n) * 128 + ks * 64 + c * 8);
            *(ushort8v*)&Bls[n * 72 + c * 8] =
                *(const ushort8v*)(Bl + (size_t)(col0 + n) * 128 + ks * 64 + c * 8);
        }
        __syncthreads();
#pragma unroll
        for (int q = 0; q < 2; ++q) {
            int ko = q * 32 + lq * 8;
            bf16x8 ah[2], al[2], bh[2], bl[2];
#pragma unroll
            for (int i = 0; i < 2; ++i) {
                ah[i] = *(const bf16x8*)&Ahs[(wm + i * 16 + lm) * 72 + ko];
                al[i] = *(const bf16x8*)&Als[(wm + i * 16 + lm) * 72 + ko];
            }
#pragma unroll
            for (int j = 0; j < 2; ++j) {
                bh[j] = *(const bf16x8*)&Bhs[(wn + j * 16 + lm) * 72 + ko];
                bl[j] = *(const bf16x8*)&Bls[(wn + j * 16 + lm) * 72 + ko];
            }
#pragma unroll
            for (int i = 0; i < 2; ++i)
#pragma unroll
                for (int j = 0; j < 2; ++j) {
                    acc[i][j] = __builtin_amdgcn_mfma_f32_16x16x32_bf16(ah[i], bh[j], acc[i][j], 0, 0, 0);
                    acc[i][j] = __builtin_amdgcn_mfma_f32_16x16x32_bf16(ah[i], bl[j], acc[i][j], 0, 0, 0);
                    acc[i][j] = __builtin_amdgcn_mfma_f32_16x16x32_bf16(al[i], bh[j], acc[i][j], 0, 0, 0);
                }
        }
    }
    // epilogue (C/D: col=lane&15, row=(lane>>4)*4+reg)
#pragma unroll
    for (int i = 0; i < 2; ++i)
#pragma unroll
        for (int reg = 0; reg < 4; ++reg) {
            int gr = row0 + wm + i * 16 + lq * 4 + reg;
            if (gr < M) {
                float sc = rowscale ? rowscale[gr] : 1.0f;
#pragma unroll
                for (int j = 0; j < 2; ++j) {
                    int col = col0 + wn + j * 16 + lm;
                    float v = acc[i][j][reg];
                    if (rowscale) v *= sc;
                    v += bias[col];
                    if (relu) v = fmaxf(v, 0.f);
                    if (postscale) v *= sc;
                    out[(size_t)gr * NC + col] = (_Float16)v;
                }
            }
        }
}

// ---------------- fused GRU step: gh = hgru @ whh^T (+b_hh), gates, in-place h update ----------------
// block: 64 rows, 4 waves x (16 rows, all 384 cols). gi precomputed (incl. b_ih), fp16.
__global__ __launch_bounds__(256) void gru_step_k(const _Float16* __restrict__ gi_t,
                                                  const unsigned short* __restrict__ whhh,
                                                  const unsigned short* __restrict__ whhl,
                                                  const float* __restrict__ b_hh,
                                                  float* __restrict__ hgru) {
    __shared__ float hs[64][132];
    int t = threadIdx.x;
    int row0 = blockIdx.x * 64;
    // stage hgru rows (fp32)
#pragma unroll
    for (int p = 0; p < 8; ++p) {
        int s = t + p * 256;             // 2048 float4 slots
        int r = s >> 5, c4 = s & 31;
        int gr = row0 + r;
        float4 v = make_float4(0.f, 0.f, 0.f, 0.f);
        if (gr < NN) v = *(const float4*)(hgru + (size_t)gr * 128 + c4 * 4);
        hs[r][c4 * 4 + 0] = v.x; hs[r][c4 * 4 + 1] = v.y;
        hs[r][c4 * 4 + 2] = v.z; hs[r][c4 * 4 + 3] = v.w;
    }
    __syncthreads();
    int w = t >> 6, lane = t & 63;
    int lm = lane & 15, lq = lane >> 4;
    int rw = w * 16;                     // wave's row base (block-local)
    // A fragments: hgru rows -> exact-ish hi/lo split, resident for all 24 n-tiles
    bf16x8 ah[4], al[4];
#pragma unroll
    for (int q = 0; q < 4; ++q) {
        cvt8 hh, ll;
#pragma unroll
        for (int j = 0; j < 8; ++j) {
            float f = hs[rw + lm][q * 32 + lq * 8 + j];
            unsigned short hb = f2bf(f);
            hh.u[j] = hb; ll.u[j] = f2bf(f - bf2f(hb));
        }
        ah[q] = hh.b; al[q] = ll.b;
    }
    f32x4 acc[24] = {};
#pragma unroll
    for (int j = 0; j < 24; ++j) {
        const unsigned short* bhp = whhh + (size_t)(j * 16 + lm) * 128 + lq * 8;
        const unsigned short* blp = whhl + (size_t)(j * 16 + lm) * 128 + lq * 8;
#pragma unroll
        for (int q = 0; q < 4; ++q) {
            bf16x8 bh = *(const bf16x8*)(bhp + q * 32);
            bf16x8 bl = *(const bf16x8*)(blp + q * 32);
            acc[j] = __builtin_amdgcn_mfma_f32_16x16x32_bf16(ah[q], bh, acc[j], 0, 0, 0);
            acc[j] = __builtin_amdgcn_mfma_f32_16x16x32_bf16(ah[q], bl, acc[j], 0, 0, 0);
            acc[j] = __builtin_amdgcn_mfma_f32_16x16x32_bf16(al[q], bh, acc[j], 0, 0, 0);
        }
    }
    // gates: acc[j]=r-pre, acc[j+8]=z-pre, acc[j+16]=n-pre at (row=rw+lq*4+reg, h=j*16+lm)
#pragma unroll
    for (int j = 0; j < 8; ++j) {
        int h = j * 16 + lm;
        float br = b_hh[h], bz = b_hh[h + 128], bn = b_hh[h + 256];
#pragma unroll
        for (int reg = 0; reg < 4; ++reg) {
            int rl = rw + lq * 4 + reg;
            int gr = row0 + rl;
            if (gr < NN) {
                const _Float16* g = gi_t + (size_t)gr * 384;
                float gir = (float)g[h], giz = (float)g[h + 128], gin = (float)g[h + 256];
                float r = 1.f / (1.f + __expf(-(gir + acc[j][reg] + br)));
                float z = 1.f / (1.f + __expf(-(giz + acc[j + 8][reg] + bz)));
                float nv = tanhf(gin + r * (acc[j + 16][reg] + bn));
                float hp = hs[rl][h];
                hgru[(size_t)gr * 128 + h] = (1.f - z) * nv + z * hp;
            }
        }
    }
}

// ---------------- decode ----------------
__global__ __launch_bounds__(256) void decode_k(const float* __restrict__ hgru,
                                                const int* __restrict__ pairs,
                                                float* __restrict__ out) {
    int gid = blockIdx.x * blockDim.x + threadIdx.x;
    int w = gid >> 6;
    int lane = threadIdx.x & 63;
    if (w >= PP) return;
    int s = pairs[w], d = pairs[PP + w];
    const float* zs = hgru + (size_t)s * HH;
    const float* zd = hgru + (size_t)d * HH;
    float acc = zs[lane] * zd[lane] + zs[lane + 64] * zd[lane + 64];
#pragma unroll
    for (int off = 32; off > 0; off >>= 1) acc += __shfl_down(acc, off);
    if (lane == 0) out[w] = acc;
}

// ---------------- orchestration ----------------
static inline size_t align256(size_t x) { return (x + 255) & ~(size_t)255; }

extern "C" void kernel_launch(void* const* d_in, const int* in_sizes, int n_in,
                              void* d_out, int out_size, void* d_ws, size_t ws_size,
                              hipStream_t stream) {
    const float* x_seq      = (const float*)d_in[0];
    const int*   edge_index = (const int*)d_in[1];
    const int*   edge_pairs = (const int*)d_in[2];
    const float* W1 = (const float*)d_in[3];
    const float* b1 = (const float*)d_in[4];
    const float* W2 = (const float*)d_in[5];
    const float* b2 = (const float*)d_in[6];
    const float* W3 = (const float*)d_in[7];
    const float* b3 = (const float*)d_in[8];
    const float* w_ih = (const float*)d_in[9];
    const float* w_hh = (const float*)d_in[10];
    const float* b_ih = (const float*)d_in[11];
    const float* b_hh = (const float*)d_in[12];

    const size_t MALL = (size_t)TT * NN;   // 320000

    char* p = (char*)d_ws;
    int*   cnt_all    = (int*)p;   p += align256(MALL * sizeof(int));
    int*   offs_all   = (int*)p;   p += align256((size_t)TT * (NN + 1) * sizeof(int));
    int*   cursor_all = (int*)p;   p += align256(MALL * sizeof(int));
    float* dinv_all   = (float*)p; p += align256(MALL * sizeof(float));
    int*   csr_all    = (int*)p;   p += align256((size_t)TT * EE * sizeof(int));
    _Float16* g   = (_Float16*)p;  p += align256(MALL * HH * sizeof(_Float16));      // 82 MB
    _Float16* a   = (_Float16*)p;  p += align256(MALL * HH * sizeof(_Float16));      // 82 MB
    _Float16* F   = (_Float16*)p;  p += align256(MALL * HH * sizeof(_Float16));      // 82 MB
    _Float16* gi  = (_Float16*)p;  p += align256(MALL * 3 * HH * sizeof(_Float16));  // 246 MB
    float* hgru = (float*)p;       p += align256((size_t)NN * HH * sizeof(float));
    unsigned short* W1h = (unsigned short*)p; p += align256(128 * 128 * 2);
    unsigned short* W1l = (unsigned short*)p; p += align256(128 * 128 * 2);
    unsigned short* W2h = (unsigned short*)p; p += align256(128 * 128 * 2);
    unsigned short* W2l = (unsigned short*)p; p += align256(128 * 128 * 2);
    unsigned short* W3h = (unsigned short*)p; p += align256(128 * 128 * 2);
    unsigned short* W3l = (unsigned short*)p; p += align256(128 * 128 * 2);
    unsigned short* wihh = (unsigned short*)p; p += align256(384 * 128 * 2);
    unsigned short* wihl = (unsigned short*)p; p += align256(384 * 128 * 2);
    unsigned short* whhh = (unsigned short*)p; p += align256(384 * 128 * 2);
    unsigned short* whhl = (unsigned short*)p; p += align256(384 * 128 * 2);

    hipMemsetAsync(hgru, 0, (size_t)NN * HH * sizeof(float), stream);
    hipMemsetAsync(cnt_all, 0, MALL * sizeof(int), stream);

    wprep_t_k<<<64, 256, 0, stream>>>(W1, W1h, W1l);
    wprep_t_k<<<64, 256, 0, stream>>>(W2, W2h, W2l);
    wprep_t_k<<<64, 256, 0, stream>>>(W3, W3h, W3l);
    wprep_d_k<<<192, 256, 0, stream>>>(w_ih, wihh, wihl, 384 * 128);
    wprep_d_k<<<192, 256, 0, stream>>>(w_hh, whhh, whhl, 384 * 128);

    // CSR for all frames
    dim3 ge((EE + 255) / 256, TT);
    hist_all_k<<<ge, 256, 0, stream>>>(edge_index, cnt_all);
    scan_all_k<<<TT, 1024, 0, stream>>>(cnt_all, offs_all, dinv_all, cursor_all);
    fill_all_k<<<ge, 256, 0, stream>>>(edge_index, cursor_all, csr_all);

    // g0 = dinv ⊙ x
    scale_k<<<(int)(MALL * 32 / 256), 256, 0, stream>>>(x_seq, dinv_all, g);

    dim3 gagg(NN / 2, TT);
    dim3 gg128((int)(MALL / 64), 2);
    dim3 gg384((int)(MALL / 64), 6);

    // layer 1: a1 = agg(g0); g1 = dinv*relu(dinv*(a1 W1) + b1)
    agg_f16_k<<<gagg, 128, 0, stream>>>(g, csr_all, offs_all, a);
    gemm_f16<<<gg128, 256, 0, stream>>>(a, W1h, W1l, g, dinv_all, b1, (int)MALL, 128, 1, 1);
    // layer 2
    agg_f16_k<<<gagg, 128, 0, stream>>>(g, csr_all, offs_all, a);
    gemm_f16<<<gg128, 256, 0, stream>>>(a, W2h, W2l, g, dinv_all, b2, (int)MALL, 128, 1, 1);
    // layer 3 (no relu, no postscale): F = dinv*(a3 W3) + b3
    agg_f16_k<<<gagg, 128, 0, stream>>>(g, csr_all, offs_all, a);
    gemm_f16<<<gg128, 256, 0, stream>>>(a, W3h, W3l, F, dinv_all, b3, (int)MALL, 128, 0, 0);

    // gi = F @ w_ih^T + b_ih   (all steps batched)
    gemm_f16<<<gg384, 256, 0, stream>>>(F, wihh, wihl, gi, nullptr, b_ih, (int)MALL, 384, 0, 0);

    // sequential GRU: fused gh-GEMM + gates, in-place hgru
    int gru_blocks = (NN + 63) / 64;
    for (int t = 0; t < TT; ++t)
        gru_step_k<<<gru_blocks, 256, 0, stream>>>(gi + (size_t)t * NN * 384,
                                                   whhh, whhl, b_hh, hgru);

    decode_k<<<(PP * 64 + 255) / 256, 256, 0, stream>>>(hgru, edge_pairs, (float*)d_out);
}

// Round 5
// 2760.816 us; speedup vs baseline: 1.0327x; 1.0327x over previous
//
#include <hip/hip_runtime.h>
#include <hip/hip_bf16.h>

#define NN 20000
#define TT 16
#define EE 320000
#define CC 128
#define HH 128
#define PP 100000

typedef __bf16 bf16x8 __attribute__((ext_vector_type(8)));
typedef float  f32x4  __attribute__((ext_vector_type(4)));
typedef unsigned short ushort4v __attribute__((ext_vector_type(4)));
typedef unsigned short ushort8v __attribute__((ext_vector_type(8)));
typedef _Float16 h2v __attribute__((ext_vector_type(2)));
typedef _Float16 h4v __attribute__((ext_vector_type(4)));

typedef union { ushort8v u; bf16x8 b; } cvt8;

__device__ __forceinline__ unsigned short f2bf(float x) {
    union { float f; unsigned u; } v; v.f = x;
    unsigned r = v.u + 0x7FFF + ((v.u >> 16) & 1);
    return (unsigned short)(r >> 16);
}
__device__ __forceinline__ float bf2f(unsigned short h) {
    union { unsigned u; float f; } v; v.u = ((unsigned)h) << 16; return v.f;
}

// ---------------- batched CSR build, XCD-pinned: frame = blockIdx.x % 16 ----------------
// With round-robin block->XCD dispatch, frame f's blocks land on XCD f%8, keeping
// that frame's counters + CSR region resident in ONE per-XCD L2 (write-combining).

__global__ void hist_all_k(const int* __restrict__ edge_index, int* __restrict__ cnt_all) {
    int b = blockIdx.x;
    int f = b & 15, chunk = b >> 4;
    int e = chunk * 256 + threadIdx.x;
    if (e < EE) {
        const int* dst = edge_index + (size_t)f * 2 * EE + EE;
        atomicAdd(&cnt_all[f * NN + dst[e]], 1);
    }
}

// one block per frame; emits offsets, dinv, and absolute csr fill cursor
__global__ __launch_bounds__(1024) void scan_all_k(const int* __restrict__ cnt_all,
                                                   int* __restrict__ offs_all,
                                                   float* __restrict__ dinv_all,
                                                   int* __restrict__ cursor_all) {
    __shared__ int part[1024];
    int f = blockIdx.x;
    const int* cnt = cnt_all + f * NN;
    int* offs = offs_all + f * (NN + 1);
    int t = threadIdx.x;
    int base = t * 20;
    int vals[20];
    int s = 0;
#pragma unroll
    for (int i = 0; i < 20; ++i) {
        int idx = base + i;
        int v = (idx < NN) ? cnt[idx] : 0;
        vals[i] = v; s += v;
    }
    part[t] = s;
    __syncthreads();
    for (int off = 1; off < 1024; off <<= 1) {
        int v = (t >= off) ? part[t - off] : 0;
        __syncthreads();
        part[t] += v;
        __syncthreads();
    }
    int run = part[t] - s;
#pragma unroll
    for (int i = 0; i < 20; ++i) {
        int idx = base + i;
        if (idx < NN) {
            offs[idx] = run;
            cursor_all[f * NN + idx] = f * EE + run;
            dinv_all[f * NN + idx] = rsqrtf((float)vals[i] + 1.0f);
            run += vals[i];
        }
    }
    if (t == 0) offs[NN] = EE;
}

__global__ void fill_all_k(const int* __restrict__ edge_index,
                           int* __restrict__ cursor_all,
                           unsigned short* __restrict__ csr_all) {
    int b = blockIdx.x;
    int f = b & 15, chunk = b >> 4;
    int e = chunk * 256 + threadIdx.x;
    if (e < EE) {
        const int* src = edge_index + (size_t)f * 2 * EE;
        const int* dst = src + EE;
        int d = dst[e];
        int pos = atomicAdd(&cursor_all[f * NN + d], 1);
        csr_all[pos] = (unsigned short)src[e];
    }
}

// ---------------- weight prep ----------------
__global__ void wprep_t_k(const float* __restrict__ W,
                          unsigned short* __restrict__ oh,
                          unsigned short* __restrict__ ol) {
    int i = blockIdx.x * blockDim.x + threadIdx.x;
    if (i >= 128 * 128) return;
    int n = i >> 7, k = i & 127;
    float v = W[k * 128 + n];
    unsigned short h = f2bf(v);
    oh[i] = h;
    ol[i] = f2bf(v - bf2f(h));
}

__global__ void wprep_d_k(const float* __restrict__ w,
                          unsigned short* __restrict__ oh,
                          unsigned short* __restrict__ ol, int n) {
    int i = blockIdx.x * blockDim.x + threadIdx.x;
    if (i >= n) return;
    float v = w[i];
    unsigned short h = f2bf(v);
    oh[i] = h;
    ol[i] = f2bf(v - bf2f(h));
}

// ---------------- g0 = dinv ⊙ x  (fp32 -> fp16) ----------------
__global__ __launch_bounds__(256) void scale_k(const float* __restrict__ x,
                                               const float* __restrict__ dinv_all,
                                               _Float16* __restrict__ g) {
    int idx = blockIdx.x * blockDim.x + threadIdx.x;   // 320000*32
    int row = idx >> 5, q = idx & 31;
    float4 v = *(const float4*)(x + (size_t)row * 128 + q * 4);
    float d = dinv_all[row];
    h4v o;
    o.x = (_Float16)(v.x * d); o.y = (_Float16)(v.y * d);
    o.z = (_Float16)(v.z * d); o.w = (_Float16)(v.w * d);
    *(h4v*)(g + (size_t)row * 128 + q * 4) = o;
}

// ---------------- aggregation (XCD-pinned): a[n] = sum_{s in N(n)} g[s] + g[n] ----------------
__global__ __launch_bounds__(128) void agg_f16_k(const _Float16* __restrict__ g,
                                                 const unsigned short* __restrict__ csr_all,
                                                 const int* __restrict__ offs_all,
                                                 _Float16* __restrict__ a) {
    int b = blockIdx.x;
    int f = b & 15, pair = b >> 4;
    int n = pair * 2 + (threadIdx.x >> 6);
    int lane = threadIdx.x & 63;
    const int* offs = offs_all + f * (NN + 1);
    const unsigned short* csr = csr_all + (size_t)f * EE;
    const _Float16* gf = g + (size_t)f * NN * HH;
    int beg = offs[n], end = offs[n + 1];
    float a0 = 0.f, a1 = 0.f;
    int e = beg;
    for (; e + 3 < end; e += 4) {
        int s0 = csr[e], s1 = csr[e + 1], s2 = csr[e + 2], s3 = csr[e + 3];
        h2v v0 = *(const h2v*)(gf + (size_t)s0 * HH + lane * 2);
        h2v v1 = *(const h2v*)(gf + (size_t)s1 * HH + lane * 2);
        h2v v2 = *(const h2v*)(gf + (size_t)s2 * HH + lane * 2);
        h2v v3 = *(const h2v*)(gf + (size_t)s3 * HH + lane * 2);
        a0 += ((float)v0.x + (float)v1.x) + ((float)v2.x + (float)v3.x);
        a1 += ((float)v0.y + (float)v1.y) + ((float)v2.y + (float)v3.y);
    }
    for (; e < end; ++e) {
        h2v v = *(const h2v*)(gf + (size_t)csr[e] * HH + lane * 2);
        a0 += (float)v.x; a1 += (float)v.y;
    }
    h2v vs = *(const h2v*)(gf + (size_t)n * HH + lane * 2);
    a0 += (float)vs.x; a1 += (float)vs.y;
    h2v r; r.x = (_Float16)a0; r.y = (_Float16)a1;
    *(h2v*)(a + ((size_t)f * NN + n) * HH + lane * 2) = r;
}

// ---------------- split-bf16 MFMA GEMM, fp16 A input, fp16 output ----------------
__global__ __launch_bounds__(256) void gemm_f16(const _Float16* __restrict__ A,
                                                const unsigned short* __restrict__ Bh,
                                                const unsigned short* __restrict__ Bl,
                                                _Float16* __restrict__ out,
                                                const float* __restrict__ rowscale,
                                                const float* __restrict__ bias,
                                                int M, int NC, int relu, int postscale) {
    __shared__ unsigned short Ahs[64 * 72], Als[64 * 72], Bhs[64 * 72], Bls[64 * 72];
    int t = threadIdx.x;
    int row0 = blockIdx.x * 64, col0 = blockIdx.y * 64;
    int w = t >> 6, lane = t & 63;
    int wm = (w & 1) * 32, wn = (w >> 1) * 32;
    int lm = lane & 15, lq = lane >> 4;
    f32x4 acc[2][2] = {};

    for (int ks = 0; ks < 2; ++ks) {
        if (ks) __syncthreads();
#pragma unroll
        for (int p = 0; p < 2; ++p) {
            int s = t + p * 256;
            int r = s >> 3, c8 = s & 7;
            int gr = row0 + r;
            h2v v4[4] = {};
            if (gr < M) {
#pragma unroll
                for (int q = 0; q < 4; ++q)
                    v4[q] = *(const h2v*)(A + (size_t)gr * 128 + ks * 64 + c8 * 8 + q * 2);
            }
            cvt8 hh, ll;
#pragma unroll
            for (int q = 0; q < 4; ++q) {
                float f0 = (float)v4[q].x, f1 = (float)v4[q].y;
                unsigned short h0 = f2bf(f0), h1 = f2bf(f1);
                hh.u[q * 2] = h0;     ll.u[q * 2] = f2bf(f0 - bf2f(h0));
                hh.u[q * 2 + 1] = h1; ll.u[q * 2 + 1] = f2bf(f1 - bf2f(h1));
            }
            *(ushort8v*)&Ahs[r * 72 + c8 * 8] = hh.u;
            *(ushort8v*)&Als[r * 72 + c8 * 8] = ll.u;
        }
#pragma unroll
        for (int p = 0; p < 2; ++p) {
            int s = t + p * 256;
            int n = s >> 3, c = s & 7;
            *(ushort8v*)&Bhs[n * 72 + c * 8] =
                *(const ushort8v*)(Bh + (size_t)(col0 + n) * 128 + ks * 64 + c * 8);
            *(ushort8v*)&Bls[n * 72 + c * 8] =
                *(const ushort8v*)(Bl + (size_t)(col0 + n) * 128 + ks * 64 + c * 8);
        }
        __syncthreads();
#pragma unroll
        for (int q = 0; q < 2; ++q) {
            int ko = q * 32 + lq * 8;
            bf16x8 ah[2], al[2], bh[2], bl[2];
#pragma unroll
            for (int i = 0; i < 2; ++i) {
                ah[i] = *(const bf16x8*)&Ahs[(wm + i * 16 + lm) * 72 + ko];
                al[i] = *(const bf16x8*)&Als[(wm + i * 16 + lm) * 72 + ko];
            }
#pragma unroll
            for (int j = 0; j < 2; ++j) {
                bh[j] = *(const bf16x8*)&Bhs[(wn + j * 16 + lm) * 72 + ko];
                bl[j] = *(const bf16x8*)&Bls[(wn + j * 16 + lm) * 72 + ko];
            }
#pragma unroll
            for (int i = 0; i < 2; ++i)
#pragma unroll
                for (int j = 0; j < 2; ++j) {
                    acc[i][j] = __builtin_amdgcn_mfma_f32_16x16x32_bf16(ah[i], bh[j], acc[i][j], 0, 0, 0);
                    acc[i][j] = __builtin_amdgcn_mfma_f32_16x16x32_bf16(ah[i], bl[j], acc[i][j], 0, 0, 0);
                    acc[i][j] = __builtin_amdgcn_mfma_f32_16x16x32_bf16(al[i], bh[j], acc[i][j], 0, 0, 0);
                }
        }
    }
#pragma unroll
    for (int i = 0; i < 2; ++i)
#pragma unroll
        for (int reg = 0; reg < 4; ++reg) {
            int gr = row0 + wm + i * 16 + lq * 4 + reg;
            if (gr < M) {
                float sc = rowscale ? rowscale[gr] : 1.0f;
#pragma unroll
                for (int j = 0; j < 2; ++j) {
                    int col = col0 + wn + j * 16 + lm;
                    float v = acc[i][j][reg];
                    if (rowscale) v *= sc;
                    v += bias[col];
                    if (relu) v = fmaxf(v, 0.f);
                    if (postscale) v *= sc;
                    out[(size_t)gr * NC + col] = (_Float16)v;
                }
            }
        }
}

// ---------------- fused GRU step ----------------
__global__ __launch_bounds__(256) void gru_step_k(const _Float16* __restrict__ gi_t,
                                                  const unsigned short* __restrict__ whhh,
                                                  const unsigned short* __restrict__ whhl,
                                                  const float* __restrict__ b_hh,
                                                  float* __restrict__ hgru) {
    __shared__ float hs[64][132];
    int t = threadIdx.x;
    int row0 = blockIdx.x * 64;
#pragma unroll
    for (int p = 0; p < 8; ++p) {
        int s = t + p * 256;
        int r = s >> 5, c4 = s & 31;
        int gr = row0 + r;
        float4 v = make_float4(0.f, 0.f, 0.f, 0.f);
        if (gr < NN) v = *(const float4*)(hgru + (size_t)gr * 128 + c4 * 4);
        hs[r][c4 * 4 + 0] = v.x; hs[r][c4 * 4 + 1] = v.y;
        hs[r][c4 * 4 + 2] = v.z; hs[r][c4 * 4 + 3] = v.w;
    }
    __syncthreads();
    int w = t >> 6, lane = t & 63;
    int lm = lane & 15, lq = lane >> 4;
    int rw = w * 16;
    bf16x8 ah[4], al[4];
#pragma unroll
    for (int q = 0; q < 4; ++q) {
        cvt8 hh, ll;
#pragma unroll
        for (int j = 0; j < 8; ++j) {
            float f = hs[rw + lm][q * 32 + lq * 8 + j];
            unsigned short hb = f2bf(f);
            hh.u[j] = hb; ll.u[j] = f2bf(f - bf2f(hb));
        }
        ah[q] = hh.b; al[q] = ll.b;
    }
    f32x4 acc[24] = {};
#pragma unroll
    for (int j = 0; j < 24; ++j) {
        const unsigned short* bhp = whhh + (size_t)(j * 16 + lm) * 128 + lq * 8;
        const unsigned short* blp = whhl + (size_t)(j * 16 + lm) * 128 + lq * 8;
#pragma unroll
        for (int q = 0; q < 4; ++q) {
            bf16x8 bh = *(const bf16x8*)(bhp + q * 32);
            bf16x8 bl = *(const bf16x8*)(blp + q * 32);
            acc[j] = __builtin_amdgcn_mfma_f32_16x16x32_bf16(ah[q], bh, acc[j], 0, 0, 0);
            acc[j] = __builtin_amdgcn_mfma_f32_16x16x32_bf16(ah[q], bl, acc[j], 0, 0, 0);
            acc[j] = __builtin_amdgcn_mfma_f32_16x16x32_bf16(al[q], bh, acc[j], 0, 0, 0);
        }
    }
#pragma unroll
    for (int j = 0; j < 8; ++j) {
        int h = j * 16 + lm;
        float br = b_hh[h], bz = b_hh[h + 128], bn = b_hh[h + 256];
#pragma unroll
        for (int reg = 0; reg < 4; ++reg) {
            int rl = rw + lq * 4 + reg;
            int gr = row0 + rl;
            if (gr < NN) {
                const _Float16* g = gi_t + (size_t)gr * 384;
                float gir = (float)g[h], giz = (float)g[h + 128], gin = (float)g[h + 256];
                float r = 1.f / (1.f + __expf(-(gir + acc[j][reg] + br)));
                float z = 1.f / (1.f + __expf(-(giz + acc[j + 8][reg] + bz)));
                float nv = tanhf(gin + r * (acc[j + 16][reg] + bn));
                float hp = hs[rl][h];
                hgru[(size_t)gr * 128 + h] = (1.f - z) * nv + z * hp;
            }
        }
    }
}

// ---------------- decode ----------------
__global__ __launch_bounds__(256) void decode_k(const float* __restrict__ hgru,
                                                const int* __restrict__ pairs,
                                                float* __restrict__ out) {
    int gid = blockIdx.x * blockDim.x + threadIdx.x;
    int w = gid >> 6;
    int lane = threadIdx.x & 63;
    if (w >= PP) return;
    int s = pairs[w], d = pairs[PP + w];
    const float* zs = hgru + (size_t)s * HH;
    const float* zd = hgru + (size_t)d * HH;
    float acc = zs[lane] * zd[lane] + zs[lane + 64] * zd[lane + 64];
#pragma unroll
    for (int off = 32; off > 0; off >>= 1) acc += __shfl_down(acc, off);
    if (lane == 0) out[w] = acc;
}

// ---------------- orchestration ----------------
static inline size_t align256(size_t x) { return (x + 255) & ~(size_t)255; }

extern "C" void kernel_launch(void* const* d_in, const int* in_sizes, int n_in,
                              void* d_out, int out_size, void* d_ws, size_t ws_size,
                              hipStream_t stream) {
    const float* x_seq      = (const float*)d_in[0];
    const int*   edge_index = (const int*)d_in[1];
    const int*   edge_pairs = (const int*)d_in[2];
    const float* W1 = (const float*)d_in[3];
    const float* b1 = (const float*)d_in[4];
    const float* W2 = (const float*)d_in[5];
    const float* b2 = (const float*)d_in[6];
    const float* W3 = (const float*)d_in[7];
    const float* b3 = (const float*)d_in[8];
    const float* w_ih = (const float*)d_in[9];
    const float* w_hh = (const float*)d_in[10];
    const float* b_ih = (const float*)d_in[11];
    const float* b_hh = (const float*)d_in[12];

    const size_t MALL = (size_t)TT * NN;   // 320000

    char* p = (char*)d_ws;
    int*   cnt_all    = (int*)p;   p += align256(MALL * sizeof(int));
    int*   offs_all   = (int*)p;   p += align256((size_t)TT * (NN + 1) * sizeof(int));
    int*   cursor_all = (int*)p;   p += align256(MALL * sizeof(int));
    float* dinv_all   = (float*)p; p += align256(MALL * sizeof(float));
    unsigned short* csr_all = (unsigned short*)p; p += align256((size_t)TT * EE * sizeof(unsigned short));
    _Float16* g   = (_Float16*)p;  p += align256(MALL * HH * sizeof(_Float16));
    _Float16* a   = (_Float16*)p;  p += align256(MALL * HH * sizeof(_Float16));
    _Float16* F   = (_Float16*)p;  p += align256(MALL * HH * sizeof(_Float16));
    _Float16* gi  = (_Float16*)p;  p += align256(MALL * 3 * HH * sizeof(_Float16));
    float* hgru = (float*)p;       p += align256((size_t)NN * HH * sizeof(float));
    unsigned short* W1h = (unsigned short*)p; p += align256(128 * 128 * 2);
    unsigned short* W1l = (unsigned short*)p; p += align256(128 * 128 * 2);
    unsigned short* W2h = (unsigned short*)p; p += align256(128 * 128 * 2);
    unsigned short* W2l = (unsigned short*)p; p += align256(128 * 128 * 2);
    unsigned short* W3h = (unsigned short*)p; p += align256(128 * 128 * 2);
    unsigned short* W3l = (unsigned short*)p; p += align256(128 * 128 * 2);
    unsigned short* wihh = (unsigned short*)p; p += align256(384 * 128 * 2);
    unsigned short* wihl = (unsigned short*)p; p += align256(384 * 128 * 2);
    unsigned short* whhh = (unsigned short*)p; p += align256(384 * 128 * 2);
    unsigned short* whhl = (unsigned short*)p; p += align256(384 * 128 * 2);

    hipMemsetAsync(hgru, 0, (size_t)NN * HH * sizeof(float), stream);
    hipMemsetAsync(cnt_all, 0, MALL * sizeof(int), stream);

    wprep_t_k<<<64, 256, 0, stream>>>(W1, W1h, W1l);
    wprep_t_k<<<64, 256, 0, stream>>>(W2, W2h, W2l);
    wprep_t_k<<<64, 256, 0, stream>>>(W3, W3h, W3l);
    wprep_d_k<<<192, 256, 0, stream>>>(w_ih, wihh, wihl, 384 * 128);
    wprep_d_k<<<192, 256, 0, stream>>>(w_hh, whhh, whhl, 384 * 128);

    // CSR build, frame-interleaved for XCD pinning (frame = blockIdx.x % 16)
    int ge = ((EE + 255) / 256) * TT;           // 1250 chunks * 16 frames
    hist_all_k<<<ge, 256, 0, stream>>>(edge_index, cnt_all);
    scan_all_k<<<TT, 1024, 0, stream>>>(cnt_all, offs_all, dinv_all, cursor_all);
    fill_all_k<<<ge, 256, 0, stream>>>(edge_index, cursor_all, csr_all);

    // g0 = dinv ⊙ x
    scale_k<<<(int)(MALL * 32 / 256), 256, 0, stream>>>(x_seq, dinv_all, g);

    int gagg = (NN / 2) * TT;                   // 10000 pairs * 16 frames, interleaved
    dim3 gg128((int)(MALL / 64), 2);
    dim3 gg384((int)(MALL / 64), 6);

    agg_f16_k<<<gagg, 128, 0, stream>>>(g, csr_all, offs_all, a);
    gemm_f16<<<gg128, 256, 0, stream>>>(a, W1h, W1l, g, dinv_all, b1, (int)MALL, 128, 1, 1);
    agg_f16_k<<<gagg, 128, 0, stream>>>(g, csr_all, offs_all, a);
    gemm_f16<<<gg128, 256, 0, stream>>>(a, W2h, W2l, g, dinv_all, b2, (int)MALL, 128, 1, 1);
    agg_f16_k<<<gagg, 128, 0, stream>>>(g, csr_all, offs_all, a);
    gemm_f16<<<gg128, 256, 0, stream>>>(a, W3h, W3l, F, dinv_all, b3, (int)MALL, 128, 0, 0);

    gemm_f16<<<gg384, 256, 0, stream>>>(F, wihh, wihl, gi, nullptr, b_ih, (int)MALL, 384, 0, 0);

    int gru_blocks = (NN + 63) / 64;
    for (int t = 0; t < TT; ++t)
        gru_step_k<<<gru_blocks, 256, 0, stream>>>(gi + (size_t)t * NN * 384,
                                                   whhh, whhl, b_hh, hgru);

    decode_k<<<(PP * 64 + 255) / 256, 256, 0, stream>>>(hgru, edge_pairs, (float*)d_out);
}

// Round 6
// 2738.639 us; speedup vs baseline: 1.0410x; 1.0081x over previous
//
#include <hip/hip_runtime.h>
#include <hip/hip_bf16.h>

#define NN 20000
#define TT 16
#define EE 320000
#define CC 128
#define HH 128
#define PP 100000
#define QN (NN / 4)   // node groups of 4 for agg

typedef __bf16 bf16x8 __attribute__((ext_vector_type(8)));
typedef float  f32x4  __attribute__((ext_vector_type(4)));
typedef unsigned short ushort4v __attribute__((ext_vector_type(4)));
typedef unsigned short ushort8v __attribute__((ext_vector_type(8)));
typedef _Float16 h2v __attribute__((ext_vector_type(2)));
typedef _Float16 h4v __attribute__((ext_vector_type(4)));

typedef union { ushort8v u; bf16x8 b; } cvt8;

__device__ __forceinline__ unsigned short f2bf(float x) {
    union { float f; unsigned u; } v; v.f = x;
    unsigned r = v.u + 0x7FFF + ((v.u >> 16) & 1);
    return (unsigned short)(r >> 16);
}
__device__ __forceinline__ float bf2f(unsigned short h) {
    union { unsigned u; float f; } v; v.u = ((unsigned)h) << 16; return v.f;
}

// ---------------- batched CSR build, XCD-pinned: frame = blockIdx.x % 16 ----------------

__global__ void hist_all_k(const int* __restrict__ edge_index, int* __restrict__ cnt_all) {
    int b = blockIdx.x;
    int f = b & 15, chunk = b >> 4;
    int e = chunk * 256 + threadIdx.x;
    if (e < EE) {
        const int* dst = edge_index + (size_t)f * 2 * EE + EE;
        atomicAdd(&cnt_all[f * NN + dst[e]], 1);
    }
}

__global__ __launch_bounds__(1024) void scan_all_k(const int* __restrict__ cnt_all,
                                                   int* __restrict__ offs_all,
                                                   float* __restrict__ dinv_all,
                                                   int* __restrict__ cursor_all) {
    __shared__ int part[1024];
    int f = blockIdx.x;
    const int* cnt = cnt_all + f * NN;
    int* offs = offs_all + f * (NN + 1);
    int t = threadIdx.x;
    int base = t * 20;
    int vals[20];
    int s = 0;
#pragma unroll
    for (int i = 0; i < 20; ++i) {
        int idx = base + i;
        int v = (idx < NN) ? cnt[idx] : 0;
        vals[i] = v; s += v;
    }
    part[t] = s;
    __syncthreads();
    for (int off = 1; off < 1024; off <<= 1) {
        int v = (t >= off) ? part[t - off] : 0;
        __syncthreads();
        part[t] += v;
        __syncthreads();
    }
    int run = part[t] - s;
#pragma unroll
    for (int i = 0; i < 20; ++i) {
        int idx = base + i;
        if (idx < NN) {
            offs[idx] = run;
            cursor_all[f * NN + idx] = f * EE + run;
            dinv_all[f * NN + idx] = rsqrtf((float)vals[i] + 1.0f);
            run += vals[i];
        }
    }
    if (t == 0) offs[NN] = EE;
}

__global__ void fill_all_k(const int* __restrict__ edge_index,
                           int* __restrict__ cursor_all,
                           unsigned short* __restrict__ csr_all) {
    int b = blockIdx.x;
    int f = b & 15, chunk = b >> 4;
    int e = chunk * 256 + threadIdx.x;
    if (e < EE) {
        const int* src = edge_index + (size_t)f * 2 * EE;
        const int* dst = src + EE;
        int d = dst[e];
        int pos = atomicAdd(&cursor_all[f * NN + d], 1);
        csr_all[pos] = (unsigned short)src[e];
    }
}

// ---------------- weight prep ----------------
__global__ void wprep_t_k(const float* __restrict__ W,
                          unsigned short* __restrict__ oh,
                          unsigned short* __restrict__ ol) {
    int i = blockIdx.x * blockDim.x + threadIdx.x;
    if (i >= 128 * 128) return;
    int n = i >> 7, k = i & 127;
    float v = W[k * 128 + n];
    unsigned short h = f2bf(v);
    oh[i] = h;
    ol[i] = f2bf(v - bf2f(h));
}

__global__ void wprep_d_k(const float* __restrict__ w,
                          unsigned short* __restrict__ oh,
                          unsigned short* __restrict__ ol, int n) {
    int i = blockIdx.x * blockDim.x + threadIdx.x;
    if (i >= n) return;
    float v = w[i];
    unsigned short h = f2bf(v);
    oh[i] = h;
    ol[i] = f2bf(v - bf2f(h));
}

// ---------------- g0 = dinv ⊙ x  (fp32 -> fp16) ----------------
__global__ __launch_bounds__(256) void scale_k(const float* __restrict__ x,
                                               const float* __restrict__ dinv_all,
                                               _Float16* __restrict__ g) {
    int idx = blockIdx.x * blockDim.x + threadIdx.x;
    int row = idx >> 5, q = idx & 31;
    float4 v = *(const float4*)(x + (size_t)row * 128 + q * 4);
    float d = dinv_all[row];
    h4v o;
    o.x = (_Float16)(v.x * d); o.y = (_Float16)(v.y * d);
    o.z = (_Float16)(v.z * d); o.w = (_Float16)(v.w * d);
    *(h4v*)(g + (size_t)row * 128 + q * 4) = o;
}

// ---------------- aggregation, feature-halved + XCD-pinned ----------------
// Block decode: xcd = b&7 (frame%8), grp middle, pass slowest (octet, then half).
// => at any time one XCD gathers from ONE frame's ONE 64-dim slice = 2.56 MB < 4 MB L2.
// 128 threads = 4 nodes x 32 lanes (each lane: 2 fp16 of the 64-dim half).
__global__ __launch_bounds__(128) void agg_half_k(const _Float16* __restrict__ g,
                                                  const unsigned short* __restrict__ csr_all,
                                                  const int* __restrict__ offs_all,
                                                  _Float16* __restrict__ a) {
    int b = blockIdx.x;
    int xcd = b & 7;
    int r1 = b >> 3;
    int grp = r1 % QN;
    int pass = r1 / QN;                 // 0..3, slowest
    int f = xcd + ((pass & 1) << 3);    // frame octet
    int hoff = (pass >> 1) * 64;        // feature half
    int t = threadIdx.x;
    int node = grp * 4 + (t >> 5);
    int lane = t & 31;
    const int* offs = offs_all + f * (NN + 1);
    const unsigned short* csr = csr_all + (size_t)f * EE;
    const _Float16* gf = g + (size_t)f * NN * HH + hoff + lane * 2;
    int beg = offs[node], end = offs[node + 1];
    float a0 = 0.f, a1 = 0.f;
    int e = beg;
    for (; e + 3 < end; e += 4) {
        int s0 = csr[e], s1 = csr[e + 1], s2 = csr[e + 2], s3 = csr[e + 3];
        h2v v0 = *(const h2v*)(gf + (size_t)s0 * HH);
        h2v v1 = *(const h2v*)(gf + (size_t)s1 * HH);
        h2v v2 = *(const h2v*)(gf + (size_t)s2 * HH);
        h2v v3 = *(const h2v*)(gf + (size_t)s3 * HH);
        a0 += ((float)v0.x + (float)v1.x) + ((float)v2.x + (float)v3.x);
        a1 += ((float)v0.y + (float)v1.y) + ((float)v2.y + (float)v3.y);
    }
    for (; e < end; ++e) {
        h2v v = *(const h2v*)(gf + (size_t)csr[e] * HH);
        a0 += (float)v.x; a1 += (float)v.y;
    }
    h2v vs = *(const h2v*)(gf + (size_t)node * HH);
    a0 += (float)vs.x; a1 += (float)vs.y;
    h2v r; r.x = (_Float16)a0; r.y = (_Float16)a1;
    *(h2v*)(a + ((size_t)f * NN + node) * HH + hoff + lane * 2) = r;
}

// ---------------- split-bf16 MFMA GEMM, fp16 A input, fp16 output ----------------
// Grid: x = col-tile (FAST, shares A row-tile via L2), y = row-tile.
__global__ __launch_bounds__(256) void gemm_f16(const _Float16* __restrict__ A,
                                                const unsigned short* __restrict__ Bh,
                                                const unsigned short* __restrict__ Bl,
                                                _Float16* __restrict__ out,
                                                const float* __restrict__ rowscale,
                                                const float* __restrict__ bias,
                                                int M, int NC, int relu, int postscale) {
    __shared__ unsigned short Ahs[64 * 72], Als[64 * 72], Bhs[64 * 72], Bls[64 * 72];
    int t = threadIdx.x;
    int row0 = blockIdx.y * 64, col0 = blockIdx.x * 64;
    int w = t >> 6, lane = t & 63;
    int wm = (w & 1) * 32, wn = (w >> 1) * 32;
    int lm = lane & 15, lq = lane >> 4;
    f32x4 acc[2][2] = {};

    for (int ks = 0; ks < 2; ++ks) {
        if (ks) __syncthreads();
#pragma unroll
        for (int p = 0; p < 2; ++p) {
            int s = t + p * 256;
            int r = s >> 3, c8 = s & 7;
            int gr = row0 + r;
            h2v v4[4] = {};
            if (gr < M) {
#pragma unroll
                for (int q = 0; q < 4; ++q)
                    v4[q] = *(const h2v*)(A + (size_t)gr * 128 + ks * 64 + c8 * 8 + q * 2);
            }
            cvt8 hh, ll;
#pragma unroll
            for (int q = 0; q < 4; ++q) {
                float f0 = (float)v4[q].x, f1 = (float)v4[q].y;
                unsigned short h0 = f2bf(f0), h1 = f2bf(f1);
                hh.u[q * 2] = h0;     ll.u[q * 2] = f2bf(f0 - bf2f(h0));
                hh.u[q * 2 + 1] = h1; ll.u[q * 2 + 1] = f2bf(f1 - bf2f(h1));
            }
            *(ushort8v*)&Ahs[r * 72 + c8 * 8] = hh.u;
            *(ushort8v*)&Als[r * 72 + c8 * 8] = ll.u;
        }
#pragma unroll
        for (int p = 0; p < 2; ++p) {
            int s = t + p * 256;
            int n = s >> 3, c = s & 7;
            *(ushort8v*)&Bhs[n * 72 + c * 8] =
                *(const ushort8v*)(Bh + (size_t)(col0 + n) * 128 + ks * 64 + c * 8);
            *(ushort8v*)&Bls[n * 72 + c * 8] =
                *(const ushort8v*)(Bl + (size_t)(col0 + n) * 128 + ks * 64 + c * 8);
        }
        __syncthreads();
#pragma unroll
        for (int q = 0; q < 2; ++q) {
            int ko = q * 32 + lq * 8;
            bf16x8 ah[2], al[2], bh[2], bl[2];
#pragma unroll
            for (int i = 0; i < 2; ++i) {
                ah[i] = *(const bf16x8*)&Ahs[(wm + i * 16 + lm) * 72 + ko];
                al[i] = *(const bf16x8*)&Als[(wm + i * 16 + lm) * 72 + ko];
            }
#pragma unroll
            for (int j = 0; j < 2; ++j) {
                bh[j] = *(const bf16x8*)&Bhs[(wn + j * 16 + lm) * 72 + ko];
                bl[j] = *(const bf16x8*)&Bls[(wn + j * 16 + lm) * 72 + ko];
            }
#pragma unroll
            for (int i = 0; i < 2; ++i)
#pragma unroll
                for (int j = 0; j < 2; ++j) {
                    acc[i][j] = __builtin_amdgcn_mfma_f32_16x16x32_bf16(ah[i], bh[j], acc[i][j], 0, 0, 0);
                    acc[i][j] = __builtin_amdgcn_mfma_f32_16x16x32_bf16(ah[i], bl[j], acc[i][j], 0, 0, 0);
                    acc[i][j] = __builtin_amdgcn_mfma_f32_16x16x32_bf16(al[i], bh[j], acc[i][j], 0, 0, 0);
                }
        }
    }
#pragma unroll
    for (int i = 0; i < 2; ++i)
#pragma unroll
        for (int reg = 0; reg < 4; ++reg) {
            int gr = row0 + wm + i * 16 + lq * 4 + reg;
            if (gr < M) {
                float sc = rowscale ? rowscale[gr] : 1.0f;
#pragma unroll
                for (int j = 0; j < 2; ++j) {
                    int col = col0 + wn + j * 16 + lm;
                    float v = acc[i][j][reg];
                    if (rowscale) v *= sc;
                    v += bias[col];
                    if (relu) v = fmaxf(v, 0.f);
                    if (postscale) v *= sc;
                    out[(size_t)gr * NC + col] = (_Float16)v;
                }
            }
        }
}

// ---------------- fused GRU step ----------------
__global__ __launch_bounds__(256) void gru_step_k(const _Float16* __restrict__ gi_t,
                                                  const unsigned short* __restrict__ whhh,
                                                  const unsigned short* __restrict__ whhl,
                                                  const float* __restrict__ b_hh,
                                                  float* __restrict__ hgru) {
    __shared__ float hs[64][132];
    int t = threadIdx.x;
    int row0 = blockIdx.x * 64;
#pragma unroll
    for (int p = 0; p < 8; ++p) {
        int s = t + p * 256;
        int r = s >> 5, c4 = s & 31;
        int gr = row0 + r;
        float4 v = make_float4(0.f, 0.f, 0.f, 0.f);
        if (gr < NN) v = *(const float4*)(hgru + (size_t)gr * 128 + c4 * 4);
        hs[r][c4 * 4 + 0] = v.x; hs[r][c4 * 4 + 1] = v.y;
        hs[r][c4 * 4 + 2] = v.z; hs[r][c4 * 4 + 3] = v.w;
    }
    __syncthreads();
    int w = t >> 6, lane = t & 63;
    int lm = lane & 15, lq = lane >> 4;
    int rw = w * 16;
    bf16x8 ah[4], al[4];
#pragma unroll
    for (int q = 0; q < 4; ++q) {
        cvt8 hh, ll;
#pragma unroll
        for (int j = 0; j < 8; ++j) {
            float f = hs[rw + lm][q * 32 + lq * 8 + j];
            unsigned short hb = f2bf(f);
            hh.u[j] = hb; ll.u[j] = f2bf(f - bf2f(hb));
        }
        ah[q] = hh.b; al[q] = ll.b;
    }
    f32x4 acc[24] = {};
#pragma unroll
    for (int j = 0; j < 24; ++j) {
        const unsigned short* bhp = whhh + (size_t)(j * 16 + lm) * 128 + lq * 8;
        const unsigned short* blp = whhl + (size_t)(j * 16 + lm) * 128 + lq * 8;
#pragma unroll
        for (int q = 0; q < 4; ++q) {
            bf16x8 bh = *(const bf16x8*)(bhp + q * 32);
            bf16x8 bl = *(const bf16x8*)(blp + q * 32);
            acc[j] = __builtin_amdgcn_mfma_f32_16x16x32_bf16(ah[q], bh, acc[j], 0, 0, 0);
            acc[j] = __builtin_amdgcn_mfma_f32_16x16x32_bf16(ah[q], bl, acc[j], 0, 0, 0);
            acc[j] = __builtin_amdgcn_mfma_f32_16x16x32_bf16(al[q], bh, acc[j], 0, 0, 0);
        }
    }
#pragma unroll
    for (int j = 0; j < 8; ++j) {
        int h = j * 16 + lm;
        float br = b_hh[h], bz = b_hh[h + 128], bn = b_hh[h + 256];
#pragma unroll
        for (int reg = 0; reg < 4; ++reg) {
            int rl = rw + lq * 4 + reg;
            int gr = row0 + rl;
            if (gr < NN) {
                const _Float16* g = gi_t + (size_t)gr * 384;
                float gir = (float)g[h], giz = (float)g[h + 128], gin = (float)g[h + 256];
                float r = 1.f / (1.f + __expf(-(gir + acc[j][reg] + br)));
                float z = 1.f / (1.f + __expf(-(giz + acc[j + 8][reg] + bz)));
                float nv = tanhf(gin + r * (acc[j + 16][reg] + bn));
                float hp = hs[rl][h];
                hgru[(size_t)gr * 128 + h] = (1.f - z) * nv + z * hp;
            }
        }
    }
}

// ---------------- decode ----------------
__global__ __launch_bounds__(256) void decode_k(const float* __restrict__ hgru,
                                                const int* __restrict__ pairs,
                                                float* __restrict__ out) {
    int gid = blockIdx.x * blockDim.x + threadIdx.x;
    int w = gid >> 6;
    int lane = threadIdx.x & 63;
    if (w >= PP) return;
    int s = pairs[w], d = pairs[PP + w];
    const float* zs = hgru + (size_t)s * HH;
    const float* zd = hgru + (size_t)d * HH;
    float acc = zs[lane] * zd[lane] + zs[lane + 64] * zd[lane + 64];
#pragma unroll
    for (int off = 32; off > 0; off >>= 1) acc += __shfl_down(acc, off);
    if (lane == 0) out[w] = acc;
}

// ---------------- orchestration ----------------
static inline size_t align256(size_t x) { return (x + 255) & ~(size_t)255; }

extern "C" void kernel_launch(void* const* d_in, const int* in_sizes, int n_in,
                              void* d_out, int out_size, void* d_ws, size_t ws_size,
                              hipStream_t stream) {
    const float* x_seq      = (const float*)d_in[0];
    const int*   edge_index = (const int*)d_in[1];
    const int*   edge_pairs = (const int*)d_in[2];
    const float* W1 = (const float*)d_in[3];
    const float* b1 = (const float*)d_in[4];
    const float* W2 = (const float*)d_in[5];
    const float* b2 = (const float*)d_in[6];
    const float* W3 = (const float*)d_in[7];
    const float* b3 = (const float*)d_in[8];
    const float* w_ih = (const float*)d_in[9];
    const float* w_hh = (const float*)d_in[10];
    const float* b_ih = (const float*)d_in[11];
    const float* b_hh = (const float*)d_in[12];

    const size_t MALL = (size_t)TT * NN;   // 320000

    char* p = (char*)d_ws;
    int*   cnt_all    = (int*)p;   p += align256(MALL * sizeof(int));
    int*   offs_all   = (int*)p;   p += align256((size_t)TT * (NN + 1) * sizeof(int));
    int*   cursor_all = (int*)p;   p += align256(MALL * sizeof(int));
    float* dinv_all   = (float*)p; p += align256(MALL * sizeof(float));
    unsigned short* csr_all = (unsigned short*)p; p += align256((size_t)TT * EE * sizeof(unsigned short));
    _Float16* g   = (_Float16*)p;  p += align256(MALL * HH * sizeof(_Float16));
    _Float16* a   = (_Float16*)p;  p += align256(MALL * HH * sizeof(_Float16));
    _Float16* F   = (_Float16*)p;  p += align256(MALL * HH * sizeof(_Float16));
    _Float16* gi  = (_Float16*)p;  p += align256(MALL * 3 * HH * sizeof(_Float16));
    float* hgru = (float*)p;       p += align256((size_t)NN * HH * sizeof(float));
    unsigned short* W1h = (unsigned short*)p; p += align256(128 * 128 * 2);
    unsigned short* W1l = (unsigned short*)p; p += align256(128 * 128 * 2);
    unsigned short* W2h = (unsigned short*)p; p += align256(128 * 128 * 2);
    unsigned short* W2l = (unsigned short*)p; p += align256(128 * 128 * 2);
    unsigned short* W3h = (unsigned short*)p; p += align256(128 * 128 * 2);
    unsigned short* W3l = (unsigned short*)p; p += align256(128 * 128 * 2);
    unsigned short* wihh = (unsigned short*)p; p += align256(384 * 128 * 2);
    unsigned short* wihl = (unsigned short*)p; p += align256(384 * 128 * 2);
    unsigned short* whhh = (unsigned short*)p; p += align256(384 * 128 * 2);
    unsigned short* whhl = (unsigned short*)p; p += align256(384 * 128 * 2);

    hipMemsetAsync(hgru, 0, (size_t)NN * HH * sizeof(float), stream);
    hipMemsetAsync(cnt_all, 0, MALL * sizeof(int), stream);

    wprep_t_k<<<64, 256, 0, stream>>>(W1, W1h, W1l);
    wprep_t_k<<<64, 256, 0, stream>>>(W2, W2h, W2l);
    wprep_t_k<<<64, 256, 0, stream>>>(W3, W3h, W3l);
    wprep_d_k<<<192, 256, 0, stream>>>(w_ih, wihh, wihl, 384 * 128);
    wprep_d_k<<<192, 256, 0, stream>>>(w_hh, whhh, whhl, 384 * 128);

    int ge = ((EE + 255) / 256) * TT;
    hist_all_k<<<ge, 256, 0, stream>>>(edge_index, cnt_all);
    scan_all_k<<<TT, 1024, 0, stream>>>(cnt_all, offs_all, dinv_all, cursor_all);
    fill_all_k<<<ge, 256, 0, stream>>>(edge_index, cursor_all, csr_all);

    scale_k<<<(int)(MALL * 32 / 256), 256, 0, stream>>>(x_seq, dinv_all, g);

    int gagg = 8 * QN * 4;                        // xcd * group * (octet,half)
    dim3 gg128(2, (int)(MALL / 64));              // col-tile fast -> A-tile L2 reuse
    dim3 gg384(6, (int)(MALL / 64));

    agg_half_k<<<gagg, 128, 0, stream>>>(g, csr_all, offs_all, a);
    gemm_f16<<<gg128, 256, 0, stream>>>(a, W1h, W1l, g, dinv_all, b1, (int)MALL, 128, 1, 1);
    agg_half_k<<<gagg, 128, 0, stream>>>(g, csr_all, offs_all, a);
    gemm_f16<<<gg128, 256, 0, stream>>>(a, W2h, W2l, g, dinv_all, b2, (int)MALL, 128, 1, 1);
    agg_half_k<<<gagg, 128, 0, stream>>>(g, csr_all, offs_all, a);
    gemm_f16<<<gg128, 256, 0, stream>>>(a, W3h, W3l, F, dinv_all, b3, (int)MALL, 128, 0, 0);

    gemm_f16<<<gg384, 256, 0, stream>>>(F, wihh, wihl, gi, nullptr, b_ih, (int)MALL, 384, 0, 0);

    int gru_blocks = (NN + 63) / 64;
    for (int t = 0; t < TT; ++t)
        gru_step_k<<<gru_blocks, 256, 0, stream>>>(gi + (size_t)t * NN * 384,
                                                   whhh, whhl, b_hh, hgru);

    decode_k<<<(PP * 64 + 255) / 256, 256, 0, stream>>>(hgru, edge_pairs, (float*)d_out);
}